// Round 7
// baseline (68.561 us; speedup 1.0000x reference)
//
#include <hip/hip_runtime.h>
#include <math.h>

// Problem constants (setup_inputs is fixed: B=64, T=512, H=768, L=400)
namespace {
constexpr int kB  = 64;
constexpr int kT  = 512;
constexpr int kH  = 768;
constexpr int kH4 = kH / 4;     // 192 float4 per row
constexpr int kHm = 767;        // H-1 feature channels
constexpr int kL  = 400;        // max_label_length
constexpr int kC  = 16;         // k-chunks
constexpr int kTC = kL / kC;    // 25 steps per chunk
constexpr int kTh = 192;        // threads: each owns 4 consecutive h
}

__device__ __forceinline__ float sigmoidf_(float x) {
  return 1.0f / (1.0f + expf(-x));
}

// One block per batch b: sigmoid+reduce alpha_sum; lane 0 walks the 400-step
// scalar recurrence emitting per-k coeffs (w,m,sel):
//   out_k = s + w*x ;  s_new = sel*s + m*x   (sel=0 at a fire resets state)
// plus per chunk c: lf[b][c] = last fire inside chunk (else -1) and
// cstart[b][c] = last fired chunk strictly before c (else 0).
__global__ __launch_bounds__(512) void k_rec(
    const float* __restrict__ hs, const int* __restrict__ labels,
    float* __restrict__ asum_ws, int* __restrict__ lf_ws,
    int* __restrict__ cstart_ws, float4* __restrict__ wms) {
  __shared__ float a_lds[kT];
  __shared__ float red[kT];
  const int b = blockIdx.x;
  const int tid = threadIdx.x;

  float sig = sigmoidf_(hs[(size_t)b * kT * kH + (size_t)tid * kH + kHm]);
  a_lds[tid] = sig;
  red[tid] = sig;
  __syncthreads();
  for (int off = 256; off > 0; off >>= 1) {
    if (tid < off) red[tid] += red[tid + off];
    __syncthreads();
  }

  if (tid == 0) {
    const float as = red[0];
    asum_ws[b] = as;
    const int lab = labels[b];
    const float len = (float)(lab < kL ? lab : kL);
    const float scale = len / as;
    float a_r = 0.0f;
    int lfc = -1;   // last fired chunk so far
    float4* wb = wms + b * kL;
    for (int c = 0; c < kC; ++c) {
      cstart_ws[b * kC + c] = lfc < 0 ? 0 : lfc;
      int lf = -1;  // last fire inside this chunk
      const int kbase = c * kTC;
#pragma unroll
      for (int kk = 0; kk < kTC; ++kk) {
        const int k = kbase + kk;
        const float ak = a_lds[k] * scale;
        const float a_a = ak + a_r;
        const bool fired = (a_a >= 1.0f);
        const float w   = fired ? (1.0f - a_r) : ak;
        const float arn = fired ? (ak - (1.0f - a_r)) : a_a;  // exact ref expr
        const float m   = fired ? arn : ak;
        const float sel = fired ? 0.0f : 1.0f;
        wb[k] = make_float4(w, m, sel, 0.0f);
        if (fired) lf = k;
        a_r = arn;
      }
      lf_ws[b * kC + c] = lf;
      if (lf >= 0) lfc = c;
    }
  }
}

// Pass 1, grid (B, kC) x 192 thr: walk [lf, chunk_end) (avg ~2-3 steps since
// fires are dense: ~len fires over 400 steps). The fire at lf resets the
// state (sel=0), so everything here is entry-state-free: store out rows
// (lf, chunk_end) directly and emit the chunk-suffix vector Q_c.
// Fire-free chunks: walk whole chunk, no stores, Q = running sum.
__global__ __launch_bounds__(kTh) void k_q(
    const float* __restrict__ hs, const int* __restrict__ labels,
    const float* __restrict__ asum_ws, const int* __restrict__ lf_ws,
    const float4* __restrict__ wms, float4* __restrict__ q_ws,
    float* __restrict__ out) {
  __shared__ float4 lw[kL];
  const int b = blockIdx.x, c = blockIdx.y, tid = threadIdx.x;

  for (int i = tid; i < kL; i += kTh) lw[i] = wms[b * kL + i];

  // n_hat = sum_b (len_b - alpha_sum_b)^2, once, in block (0,0)
  if (b == 0 && c == 0 && tid < kB) {
    const float as = asum_ws[tid];
    const int lab = labels[tid];
    const float len = (float)(lab < kL ? lab : kL);
    const float d = len - as;
    float v = d * d;
    for (int off = 32; off > 0; off >>= 1) v += __shfl_down(v, off, 64);
    if (tid == 0) out[(size_t)kB * kL * kHm] = v;
  }
  __syncthreads();

  const int lf = __builtin_amdgcn_readfirstlane(lf_ws[b * kC + c]);
  const int cb = c * kTC, ce = cb + kTC;
  const bool haslf = (lf >= 0);
  const int start = haslf ? lf : cb;

  const float4* __restrict__ px = (const float4*)(hs + (size_t)b * kT * kH) + tid;
  const int h0 = 4 * tid;
  float* __restrict__ po = out + (size_t)b * kL * kHm + h0;
  const bool w3 = (h0 + 3 < kHm);

  float4 s = make_float4(0.f, 0.f, 0.f, 0.f);
  for (int k = start; k < ce; ++k) {
    const float4 x = px[(size_t)k * kH4];
    const float4 cf = lw[k];
    if (haslf && k > lf) {  // uniform: rows after the reset are entry-free
      float* r = po + (size_t)k * kHm;
      __builtin_nontemporal_store(fmaf(cf.x, x.x, s.x), r + 0);
      __builtin_nontemporal_store(fmaf(cf.x, x.y, s.y), r + 1);
      __builtin_nontemporal_store(fmaf(cf.x, x.z, s.z), r + 2);
      if (w3) __builtin_nontemporal_store(fmaf(cf.x, x.w, s.w), r + 3);
    }
    s.x = fmaf(cf.y, x.x, cf.z * s.x);
    s.y = fmaf(cf.y, x.y, cf.z * s.y);
    s.z = fmaf(cf.y, x.z, cf.z * s.z);
    s.w = fmaf(cf.y, x.w, cf.z * s.w);
  }
  q_ws[(size_t)(b * kC + c) * kH4 + tid] = s;
}

// Pass 2, grid (B, kC) x 192 thr: entry = sum_{j in [cstart, c)} Q_j (avg 1
// load: dense fires make cstart = c-1 almost always), then a fixed fully
// unrolled 25-step loop storing rows [cb, lf] (pass 1 owns the rest).
__global__ __launch_bounds__(kTh) void k_scan(
    const float* __restrict__ hs, const int* __restrict__ lf_ws,
    const int* __restrict__ cstart_ws, const float4* __restrict__ wms,
    const float4* __restrict__ q_ws, float* __restrict__ out) {
  __shared__ float4 lw[kL];
  const int b = blockIdx.x, c = blockIdx.y, tid = threadIdx.x;

  for (int i = tid; i < kL; i += kTh) lw[i] = wms[b * kL + i];
  __syncthreads();

  const int lf = __builtin_amdgcn_readfirstlane(lf_ws[b * kC + c]);
  const int cs = __builtin_amdgcn_readfirstlane(cstart_ws[b * kC + c]);
  const int cb = c * kTC;
  const int kend = (lf >= 0) ? lf : (cb + kTC - 1);  // inclusive store end

  float4 s = make_float4(0.f, 0.f, 0.f, 0.f);
  {
    const float4* qb = q_ws + (size_t)b * kC * kH4 + tid;
    for (int j = cs; j < c; ++j) {  // avg 1 iteration (uniform bounds)
      const float4 q = qb[(size_t)j * kH4];
      s.x += q.x; s.y += q.y; s.z += q.z; s.w += q.w;
    }
  }

  const float4* __restrict__ px = (const float4*)(hs + (size_t)b * kT * kH) + tid;
  const int h0 = 4 * tid;
  float* __restrict__ po = out + (size_t)b * kL * kHm + h0;
  const bool w3 = (h0 + 3 < kHm);

#pragma unroll
  for (int kk = 0; kk < kTC; ++kk) {
    const int k = cb + kk;
    const float4 x = px[(size_t)k * kH4];   // unconditional: batchable
    const float4 cf = lw[k];
    if (k <= kend) {  // uniform store guard
      float* r = po + (size_t)k * kHm;
      __builtin_nontemporal_store(fmaf(cf.x, x.x, s.x), r + 0);
      __builtin_nontemporal_store(fmaf(cf.x, x.y, s.y), r + 1);
      __builtin_nontemporal_store(fmaf(cf.x, x.z, s.z), r + 2);
      if (w3) __builtin_nontemporal_store(fmaf(cf.x, x.w, s.w), r + 3);
    }
    s.x = fmaf(cf.y, x.x, cf.z * s.x);
    s.y = fmaf(cf.y, x.y, cf.z * s.y);
    s.z = fmaf(cf.y, x.z, cf.z * s.z);
    s.w = fmaf(cf.y, x.w, cf.z * s.w);
  }
}

extern "C" void kernel_launch(void* const* d_in, const int* in_sizes, int n_in,
                              void* d_out, int out_size, void* d_ws, size_t ws_size,
                              hipStream_t stream) {
  const float* hs     = (const float*)d_in[0];
  const int*   labels = (const int*)d_in[1];
  float* out = (float*)d_out;

  // ws layout: [0,256) alpha_sum; [256,4352) lf (64x16 i32); [4608,8704)
  // cstart; [16384, +410KB) coeff float4 per (b,k); [442368, +3.1MB) Q.
  float*  asum_ws   = (float*)d_ws;
  int*    lf_ws     = (int*)((char*)d_ws + 256);
  int*    cstart_ws = (int*)((char*)d_ws + 4608);
  float4* wms       = (float4*)((char*)d_ws + 16384);
  float4* q_ws      = (float4*)((char*)d_ws + 442368);

  k_rec<<<kB, 512, 0, stream>>>(hs, labels, asum_ws, lf_ws, cstart_ws, wms);
  k_q<<<dim3(kB, kC), kTh, 0, stream>>>(hs, labels, asum_ws, lf_ws, wms, q_ws,
                                        out);
  k_scan<<<dim3(kB, kC), kTh, 0, stream>>>(hs, lf_ws, cstart_ws, wms, q_ws,
                                           out);
}

// Round 9
// 61.921 us; speedup vs baseline: 1.1072x; 1.1072x over previous
//
#include <hip/hip_runtime.h>
#include <math.h>
#include <stdint.h>

// Problem constants (setup_inputs is fixed: B=64, T=512, H=768, L=400)
namespace {
constexpr int kB  = 64;
constexpr int kT  = 512;
constexpr int kH  = 768;
constexpr int kH4 = kH / 4;     // 192 float4 per row
constexpr int kHm = 767;        // H-1 feature channels
constexpr int kL  = 400;        // max_label_length
constexpr int kC  = 16;         // k-chunks
constexpr int kTC = kL / kC;    // 25 steps per chunk
constexpr int kTh = 192;        // threads: each owns 4 consecutive h
constexpr int kBR = 5;          // rows per staged batch (25 = 5*5)
}

typedef float f4 __attribute__((ext_vector_type(4)));

__device__ __forceinline__ float sigmoidf_(float x) {
  return 1.0f / (1.0f + expf(-x));
}
__device__ __forceinline__ f4 fma4(float a, f4 x, f4 c) {
  f4 r;
  r.x = fmaf(a, x.x, c.x); r.y = fmaf(a, x.y, c.y);
  r.z = fmaf(a, x.z, c.z); r.w = fmaf(a, x.w, c.w);
  return r;
}
__device__ __forceinline__ f4 mul4(float a, f4 x) {
  f4 r; r.x = a * x.x; r.y = a * x.y; r.z = a * x.z; r.w = a * x.w;
  return r;
}

#define VMWAIT(N)                                          \
  do {                                                     \
    asm volatile("s_waitcnt vmcnt(" #N ")" ::: "memory");  \
    __builtin_amdgcn_sched_barrier(0);                     \
  } while (0)
#define BAR()                                              \
  do {                                                     \
    asm volatile("" ::: "memory");                         \
    __builtin_amdgcn_s_barrier();                          \
    asm volatile("" ::: "memory");                         \
  } while (0)

// ---------------- k_rec: one block per batch b (512 threads) ---------------
// sigmoid row + EXACT tree-reduce alpha_sum (validated R1-R7 rounding).
// Lane 0 walks only the scalar a_r chain (dependent ops ~14cy/step) writing
// the pre-step state arp[k]; then 400 threads emit (w,m,sel) in parallel.
// Chain and emission share __f*_rn expressions so fire decisions match
// bitwise between the two sites (no fp-contract divergence).
__global__ __launch_bounds__(512) void k_rec(
    const float* __restrict__ hs, const int* __restrict__ labels,
    float* __restrict__ asum_ws, int* __restrict__ lf_ws,
    int* __restrict__ cstart_ws, f4* __restrict__ wms4) {
  __shared__ float a_lds[kT];
  __shared__ float red[kT];
  __shared__ float arp[kL];
  const int b = blockIdx.x;
  const int tid = threadIdx.x;

  const float sg = sigmoidf_(hs[(size_t)b * kT * kH + (size_t)tid * kH + kHm]);
  a_lds[tid] = sg;
  red[tid] = sg;
  __syncthreads();
  for (int off = 256; off > 0; off >>= 1) {
    if (tid < off) red[tid] += red[tid + off];
    __syncthreads();
  }

  const float as = red[0];
  const int lab = labels[b];
  const float len = (float)(lab < kL ? lab : kL);
  const float scale = len / as;

  if (tid == 0) {
    asum_ws[b] = as;
    float a_r = 0.0f;
    int lfc = -1;
    for (int c = 0; c < kC; ++c) {
      cstart_ws[b * kC + c] = lfc < 0 ? 0 : lfc;
      int lf = -1;
#pragma unroll
      for (int kk = 0; kk < kTC; ++kk) {
        const int k = c * kTC + kk;
        arp[k] = a_r;
        const float ak  = __fmul_rn(a_lds[k], scale);
        const float a_a = __fadd_rn(ak, a_r);
        const bool fired = (a_a >= 1.0f);
        const float arn = fired ? __fsub_rn(ak, __fsub_rn(1.0f, a_r)) : a_a;
        if (fired) lf = k;
        a_r = arn;
      }
      lf_ws[b * kC + c] = lf;
      if (lf >= 0) lfc = c;
    }
  }
  __syncthreads();

  if (tid < kL) {
    const float a_r = arp[tid];
    const float ak  = __fmul_rn(a_lds[tid], scale);
    const float a_a = __fadd_rn(ak, a_r);
    const bool fired = (a_a >= 1.0f);
    const float arn = fired ? __fsub_rn(ak, __fsub_rn(1.0f, a_r)) : a_a;
    const float w   = fired ? __fsub_rn(1.0f, a_r) : ak;
    const float m   = fired ? arn : ak;
    const float sel = fired ? 0.0f : 1.0f;
    f4 cf; cf.x = w; cf.y = m; cf.z = sel; cf.w = 0.0f;
    wms4[(size_t)b * kL + tid] = cf;
  }
}

// ---------------- k_q: per (b,c), 192 threads -------------------------------
// Walk [last-fire, chunk_end) (avg ~2-3 rows; fires are dense). Rows after
// the fire are entry-state-free: store them directly (disjoint from k_scan's
// rows) and emit the chunk-suffix vector Q_c. Fire-free chunk: full 25-row
// walk, no stores, Q = running sum.
__global__ __launch_bounds__(kTh) void k_q(
    const float* __restrict__ hs, const int* __restrict__ labels,
    const float* __restrict__ asum_ws, const int* __restrict__ lf_ws,
    const f4* __restrict__ wms4, f4* __restrict__ q_ws,
    float* __restrict__ out, float* __restrict__ scrap) {
  __shared__ f4 lwl[kTC];
  const int b = blockIdx.x, c = blockIdx.y, tid = threadIdx.x;

  if (tid < kTC) lwl[tid] = wms4[(size_t)b * kL + c * kTC + tid];

  if (b == 0 && c == 0 && tid < kB) {  // n_hat, once
    const float as = asum_ws[tid];
    const int lab = labels[tid];
    const float len = (float)(lab < kL ? lab : kL);
    const float d = len - as;
    float v = d * d;
    for (int off = 32; off > 0; off >>= 1) v += __shfl_down(v, off, 64);
    if (tid == 0) out[(size_t)kB * kL * kHm] = v;
  }
  __syncthreads();

  const int lf = __builtin_amdgcn_readfirstlane(lf_ws[b * kC + c]);
  const int cb = c * kTC, ce = cb + kTC;
  const bool haslf = (lf >= 0);
  const int start = haslf ? lf : cb;

  const f4* __restrict__ px = (const f4*)(hs + (size_t)b * kT * kH) + tid;
  float* po = out + (size_t)b * kL * kHm + 4 * tid;
  const bool w3 = (4 * tid + 3 < kHm);

  f4 s = {0.f, 0.f, 0.f, 0.f};
  for (int k = start; k < ce; ++k) {
    const f4 x = px[(size_t)k * kH4];
    const f4 cf = lwl[k - cb];
    if (haslf && k > lf) {  // uniform: entry-free rows, k_scan skips them
      const f4 o = fma4(cf.x, x, s);
      float* rp = po + (size_t)k * kHm;
      rp[0] = o.x; rp[1] = o.y; rp[2] = o.z;
      *(w3 ? rp + 3 : scrap) = o.w;
    }
    s = fma4(cf.y, x, mul4(cf.z, s));
  }
  q_ws[(size_t)(b * kC + c) * kTh + tid] = s;
}

// ---------------- k_scan: per (b,c), 192 threads (3 waves) ------------------
// Stage kBR rows into LDS via global_load_lds (no dest register: compiler
// cannot misschedule the data), double-buffered, counted vmcnt: after issuing
// the NEXT batch's 5 staging loads, "vmcnt(5)" leaves only those 5 in flight,
// so the current batch + all prior stores are retired (in-order vmcnt) --
// correct regardless of how the compiler merged store instructions.
__device__ __forceinline__ void stage5(const float* hsb, float* xb, int row0,
                                       int wv, int ln) {
#pragma unroll
  for (int t = 0; t < kBR; ++t) {
    // wave wv stages third wv of row row0+t -> LDS bytes [(wv+3t)*1024 ...)
    const float* src = hsb + (size_t)(row0 + t) * kH + wv * 256 + ln * 4;
    __builtin_amdgcn_global_load_lds(
        (const __attribute__((address_space(1))) uint32_t*)src,
        (__attribute__((address_space(3))) uint32_t*)&xb[(wv + 3 * t) * 256],
        16, 0, 0);
  }
}

__device__ __forceinline__ void comp5(const float* xb, const f4* lwl, int bi,
                                      int cb, int kend, float* po,
                                      float* scrap, bool w3, int tid, f4& s) {
#pragma unroll
  for (int r = 0; r < kBR; ++r) {
    const int kk = bi * kBR + r;
    const int k = cb + kk;
    const f4 cf = lwl[kk];
    const f4 x = *(const f4*)&xb[r * kH + 4 * tid];
    if (k <= kend) {  // uniform store guard (k_q owns rows after the fire)
      const f4 o = fma4(cf.x, x, s);
      float* rp = po + (size_t)k * kHm;
      rp[0] = o.x; rp[1] = o.y; rp[2] = o.z;
      *(w3 ? rp + 3 : scrap) = o.w;
    }
    s = fma4(cf.y, x, mul4(cf.z, s));
  }
}

__global__ __launch_bounds__(kTh) void k_scan(
    const float* __restrict__ hs, const int* __restrict__ lf_ws,
    const int* __restrict__ cstart_ws, const f4* __restrict__ wms4,
    const f4* __restrict__ q_ws, float* __restrict__ out,
    float* __restrict__ scrap) {
  __shared__ f4 lwl[kTC];
  __shared__ float xbuf[2][kBR * kH];  // 2 x 15 KB
  const int b = blockIdx.x, c = blockIdx.y, tid = threadIdx.x;
  const int wv = tid >> 6, ln = tid & 63;

  if (tid < kTC) lwl[tid] = wms4[(size_t)b * kL + c * kTC + tid];
  __syncthreads();

  const int lf = __builtin_amdgcn_readfirstlane(lf_ws[b * kC + c]);
  const int cs = __builtin_amdgcn_readfirstlane(cstart_ws[b * kC + c]);
  const int cb = c * kTC;
  const int kend = (lf >= 0) ? lf : (cb + kTC - 1);  // inclusive store end

  f4 s = {0.f, 0.f, 0.f, 0.f};
  {  // entry state: avg 1 L2-hot load (dense fires => cs == c-1 usually)
    const f4* qb = q_ws + (size_t)b * kC * kTh + tid;
    for (int j = cs; j < c; ++j) s += qb[(size_t)j * kTh];
  }

  const float* hsb = hs + (size_t)b * kT * kH;
  float* po = out + (size_t)b * kL * kHm + 4 * tid;
  const bool w3 = (4 * tid + 3 < kHm);
  const f4* lwp = (const f4*)lwl;

  stage5(hsb, xbuf[0], cb, wv, ln);           // batch 0
  stage5(hsb, xbuf[1], cb + kBR, wv, ln);     // batch 1
  VMWAIT(5); BAR();
  comp5(xbuf[0], lwp, 0, cb, kend, po, scrap, w3, tid, s);
  BAR();
  stage5(hsb, xbuf[0], cb + 2 * kBR, wv, ln); // batch 2
  VMWAIT(5); BAR();
  comp5(xbuf[1], lwp, 1, cb, kend, po, scrap, w3, tid, s);
  BAR();
  stage5(hsb, xbuf[1], cb + 3 * kBR, wv, ln); // batch 3
  VMWAIT(5); BAR();
  comp5(xbuf[0], lwp, 2, cb, kend, po, scrap, w3, tid, s);
  BAR();
  stage5(hsb, xbuf[0], cb + 4 * kBR, wv, ln); // batch 4
  VMWAIT(5); BAR();
  comp5(xbuf[1], lwp, 3, cb, kend, po, scrap, w3, tid, s);
  BAR();
  VMWAIT(0); BAR();                           // final: full drain (safe)
  comp5(xbuf[0], lwp, 4, cb, kend, po, scrap, w3, tid, s);
}

extern "C" void kernel_launch(void* const* d_in, const int* in_sizes, int n_in,
                              void* d_out, int out_size, void* d_ws, size_t ws_size,
                              hipStream_t stream) {
  const float* hs     = (const float*)d_in[0];
  const int*   labels = (const int*)d_in[1];
  float* out = (float*)d_out;

  // ws: [0,256) asum; [256,4352) lf (64x16 i32); [4608,8704) cstart;
  // [8704] scrap; [16384, +409.6KB) coeff f4; [442368, +3.15MB) Q vectors.
  float* asum_ws   = (float*)d_ws;
  int*   lf_ws     = (int*)((char*)d_ws + 256);
  int*   cstart_ws = (int*)((char*)d_ws + 4608);
  float* scrap     = (float*)((char*)d_ws + 8704);
  f4*    wms4      = (f4*)((char*)d_ws + 16384);
  f4*    q_ws      = (f4*)((char*)d_ws + 442368);

  k_rec<<<kB, 512, 0, stream>>>(hs, labels, asum_ws, lf_ws, cstart_ws, wms4);
  k_q<<<dim3(kB, kC), kTh, 0, stream>>>(hs, labels, asum_ws, lf_ws, wms4,
                                        q_ws, out, scrap);
  k_scan<<<dim3(kB, kC), kTh, 0, stream>>>(hs, lf_ws, cstart_ws, wms4, q_ws,
                                           out, scrap);
}

// Round 10
// 60.176 us; speedup vs baseline: 1.1394x; 1.0290x over previous
//
#include <hip/hip_runtime.h>
#include <math.h>
#include <stdint.h>

// Problem constants (setup_inputs is fixed: B=64, T=512, H=768, L=400)
namespace {
constexpr int kB  = 64;
constexpr int kT  = 512;
constexpr int kH  = 768;
constexpr int kH4 = kH / 4;     // 192 float4 per row
constexpr int kHm = 767;        // H-1 feature channels
constexpr int kL  = 400;        // max_label_length
constexpr int kC  = 16;         // k-chunks
constexpr int kTC = kL / kC;    // 25 steps per chunk
constexpr int kTh = 192;        // threads: each owns 4 consecutive h
}

typedef float f4 __attribute__((ext_vector_type(4)));

__device__ __forceinline__ float sigmoidf_(float x) {
  return 1.0f / (1.0f + expf(-x));
}
__device__ __forceinline__ f4 fma4(float a, f4 x, f4 c) {
  f4 r;
  r.x = fmaf(a, x.x, c.x); r.y = fmaf(a, x.y, c.y);
  r.z = fmaf(a, x.z, c.z); r.w = fmaf(a, x.w, c.w);
  return r;
}
__device__ __forceinline__ f4 mul4(float a, f4 x) {
  f4 r; r.x = a * x.x; r.y = a * x.y; r.z = a * x.z; r.w = a * x.w;
  return r;
}

// ---------------- k_rec: one block per batch b (512 threads) ---------------
// (unchanged from R9 -- proven) sigmoid row + EXACT tree-reduce alpha_sum;
// lane 0 walks only the scalar a_r chain writing pre-step states; 400
// threads then emit (w,m,sel) in parallel with bitwise-matching __f*_rn ops.
__global__ __launch_bounds__(512) void k_rec(
    const float* __restrict__ hs, const int* __restrict__ labels,
    float* __restrict__ asum_ws, int* __restrict__ lf_ws,
    int* __restrict__ cstart_ws, f4* __restrict__ wms4) {
  __shared__ float a_lds[kT];
  __shared__ float red[kT];
  __shared__ float arp[kL];
  const int b = blockIdx.x;
  const int tid = threadIdx.x;

  const float sg = sigmoidf_(hs[(size_t)b * kT * kH + (size_t)tid * kH + kHm]);
  a_lds[tid] = sg;
  red[tid] = sg;
  __syncthreads();
  for (int off = 256; off > 0; off >>= 1) {
    if (tid < off) red[tid] += red[tid + off];
    __syncthreads();
  }

  const float as = red[0];
  const int lab = labels[b];
  const float len = (float)(lab < kL ? lab : kL);
  const float scale = len / as;

  if (tid == 0) {
    asum_ws[b] = as;
    float a_r = 0.0f;
    int lfc = -1;
    for (int c = 0; c < kC; ++c) {
      cstart_ws[b * kC + c] = lfc < 0 ? 0 : lfc;
      int lf = -1;
#pragma unroll
      for (int kk = 0; kk < kTC; ++kk) {
        const int k = c * kTC + kk;
        arp[k] = a_r;
        const float ak  = __fmul_rn(a_lds[k], scale);
        const float a_a = __fadd_rn(ak, a_r);
        const bool fired = (a_a >= 1.0f);
        const float arn = fired ? __fsub_rn(ak, __fsub_rn(1.0f, a_r)) : a_a;
        if (fired) lf = k;
        a_r = arn;
      }
      lf_ws[b * kC + c] = lf;
      if (lf >= 0) lfc = c;
    }
  }
  __syncthreads();

  if (tid < kL) {
    const float a_r = arp[tid];
    const float ak  = __fmul_rn(a_lds[tid], scale);
    const float a_a = __fadd_rn(ak, a_r);
    const bool fired = (a_a >= 1.0f);
    const float arn = fired ? __fsub_rn(ak, __fsub_rn(1.0f, a_r)) : a_a;
    const float w   = fired ? __fsub_rn(1.0f, a_r) : ak;
    const float m   = fired ? arn : ak;
    const float sel = fired ? 0.0f : 1.0f;
    f4 cf; cf.x = w; cf.y = m; cf.z = sel; cf.w = 0.0f;
    wms4[(size_t)b * kL + tid] = cf;
  }
}

// ---------------- k_q: per (b,c), 192 threads -------------------------------
// Pure Q-vector pass (no out stores): walk [last-fire-or-chunk-begin, ce)
// (bounded <= 25 rows, avg ~3 -- fires are dense) with plain f4 loads,
// emitting the chunk-suffix state Q_c. Also computes n_hat once.
__global__ __launch_bounds__(kTh) void k_q(
    const float* __restrict__ hs, const int* __restrict__ labels,
    const float* __restrict__ asum_ws, const int* __restrict__ lf_ws,
    const f4* __restrict__ wms4, f4* __restrict__ q_ws,
    float* __restrict__ out) {
  __shared__ f4 lwl[kTC];
  const int b = blockIdx.x, c = blockIdx.y, tid = threadIdx.x;

  if (tid < kTC) lwl[tid] = wms4[(size_t)b * kL + c * kTC + tid];

  if (b == 0 && c == 0 && tid < kB) {  // n_hat, once
    const float as = asum_ws[tid];
    const int lab = labels[tid];
    const float len = (float)(lab < kL ? lab : kL);
    const float d = len - as;
    float v = d * d;
    for (int off = 32; off > 0; off >>= 1) v += __shfl_down(v, off, 64);
    if (tid == 0) out[(size_t)kB * kL * kHm] = v;
  }
  __syncthreads();

  const int lf = __builtin_amdgcn_readfirstlane(lf_ws[b * kC + c]);
  const int cb = c * kTC, ce = cb + kTC;
  const int start = (lf >= 0) ? lf : cb;  // fire resets (sel=0): exact suffix

  const f4* __restrict__ px = (const f4*)(hs + (size_t)b * kT * kH) + tid;
  f4 s = {0.f, 0.f, 0.f, 0.f};
  for (int k = start; k < ce; ++k) {
    const f4 x = px[(size_t)k * kH4];
    const f4 cf = lwl[k - cb];
    s = fma4(cf.y, x, mul4(cf.z, s));
  }
  q_ws[(size_t)(b * kC + c) * kTh + tid] = s;
}

// ---------------- k_scan: per (b,c), 192 threads, 75 KB LDS -----------------
// ONE staging burst: 25 global_load_lds per wave (25 KB/wave in flight),
// ONE drain, ONE barrier, then compute+store all 25 rows from LDS.
// 2 blocks/CU co-resident (150 KB LDS) give cross-block stage/compute
// overlap -- no intra-block pipeline, no counted vmcnt bookkeeping.
// Entry state = sum of Q_j, j in [cstart, c) (avg 1 L2-hot load). Rows at or
// after the chunk's own fire are bitwise-unaffected by entry state (sel=0
// multiplies it away), so storing all 25 rows here matches R9's split output.
__global__ __launch_bounds__(kTh) void k_scan(
    const float* __restrict__ hs, const int* __restrict__ cstart_ws,
    const f4* __restrict__ wms4, const f4* __restrict__ q_ws,
    float* __restrict__ out, float* __restrict__ scrap) {
  __shared__ f4 lwl[kTC];
  __shared__ float xl[kTC][kH];   // 75 KB
  const int b = blockIdx.x, c = blockIdx.y, tid = threadIdx.x;
  const int wv = tid >> 6, ln = tid & 63;
  const int cb = c * kTC;

  // Staging burst first: starts HBM reads as early as possible.
  const float* hsb = hs + (size_t)b * kT * kH;
#pragma unroll
  for (int r = 0; r < kTC; ++r) {
    const float* src = hsb + (size_t)(cb + r) * kH + wv * 256 + ln * 4;
    __builtin_amdgcn_global_load_lds(
        (const __attribute__((address_space(1))) uint32_t*)src,
        (__attribute__((address_space(3))) uint32_t*)&xl[r][wv * 256],
        16, 0, 0);
  }

  // Chunk coeffs -> LDS (value-wait drains staging too; that's fine, it all
  // must be done before the barrier anyway).
  if (tid < kTC) lwl[tid] = wms4[(size_t)b * kL + cb + tid];

  // Entry state from Q vectors (plain loads, avg 1 iteration).
  const int cs = __builtin_amdgcn_readfirstlane(cstart_ws[b * kC + c]);
  f4 s = {0.f, 0.f, 0.f, 0.f};
  {
    const f4* qb = q_ws + (size_t)b * kC * kTh + tid;
    for (int j = cs; j < c; ++j) s += qb[(size_t)j * kTh];
  }

  asm volatile("s_waitcnt vmcnt(0) lgkmcnt(0)" ::: "memory");
  __builtin_amdgcn_sched_barrier(0);
  __builtin_amdgcn_s_barrier();

  float* po = out + (size_t)b * kL * kHm + 4 * tid;
  const bool w3 = (4 * tid + 3 < kHm);  // only tid 191 redirects lane 3

#pragma unroll
  for (int kk = 0; kk < kTC; ++kk) {
    const f4 cf = lwl[kk];
    const f4 x = *(const f4*)&xl[kk][4 * tid];  // 2-way b128 conflict: free
    const f4 o = fma4(cf.x, x, s);
    float* rp = po + (size_t)(cb + kk) * kHm;
    rp[0] = o.x; rp[1] = o.y; rp[2] = o.z;
    *(w3 ? rp + 3 : scrap) = o.w;               // branchless partial lane
    s = fma4(cf.y, x, mul4(cf.z, s));
  }
}

extern "C" void kernel_launch(void* const* d_in, const int* in_sizes, int n_in,
                              void* d_out, int out_size, void* d_ws, size_t ws_size,
                              hipStream_t stream) {
  const float* hs     = (const float*)d_in[0];
  const int*   labels = (const int*)d_in[1];
  float* out = (float*)d_out;

  // ws: [0,256) asum; [256,4352) lf (64x16 i32); [4608,8704) cstart;
  // [8704] scrap; [16384, +409.6KB) coeff f4; [442368, +3.15MB) Q vectors.
  float* asum_ws   = (float*)d_ws;
  int*   lf_ws     = (int*)((char*)d_ws + 256);
  int*   cstart_ws = (int*)((char*)d_ws + 4608);
  float* scrap     = (float*)((char*)d_ws + 8704);
  f4*    wms4      = (f4*)((char*)d_ws + 16384);
  f4*    q_ws      = (f4*)((char*)d_ws + 442368);

  k_rec<<<kB, 512, 0, stream>>>(hs, labels, asum_ws, lf_ws, cstart_ws, wms4);
  k_q<<<dim3(kB, kC), kTh, 0, stream>>>(hs, labels, asum_ws, lf_ws, wms4,
                                        q_ws, out);
  k_scan<<<dim3(kB, kC), kTh, 0, stream>>>(hs, cstart_ws, wms4, q_ws, out,
                                           scrap);
}